// Round 5
// baseline (795.634 us; speedup 1.0000x reference)
//
#include <hip/hip_runtime.h>
#include <hip/hip_cooperative_groups.h>

namespace cg = cooperative_groups;

// GCN aggregation: out[t] = norm[t] * sum_{e:dst=t} norm[src_e]*x[src_e] + EPS*x[t]
// Round 5: ONE cooperative kernel, linked-list CSR (atomicExch chain heads +
// coalesced (src,next) pair stores), bf16 y = norm*x for the gather.
// Random-op count per edge: 1 fire-forget atomicAdd (deg) + 1 atomicExch (head).
constexpr int D   = 64;
constexpr float EPS = 0.5f;
constexpr int GRID = 1024;   // 4 blocks/CU x 256 CUs — guaranteed co-resident
constexpr int BLK  = 256;

static_assert(D == 64, "shift constants assume D=64");

__device__ __forceinline__ unsigned int f2bf(float f) {
    unsigned int u = __float_as_uint(f);
    return (u + 0x7FFFu + ((u >> 16) & 1u)) >> 16;   // RNE to bf16
}
__device__ __forceinline__ float bf2f_lo(unsigned int v) { return __uint_as_float(v << 16); }
__device__ __forceinline__ float bf2f_hi(unsigned int v) { return __uint_as_float(v & 0xFFFF0000u); }

__global__ __launch_bounds__(BLK, 4)
void gcn_fused(const float* __restrict__ x, const int* __restrict__ src,
               const int* __restrict__ dst, float* __restrict__ out,
               int2* __restrict__ pairs, int* __restrict__ head,
               int* __restrict__ deg, float* __restrict__ norm,
               unsigned int* __restrict__ yh, int n, int E, int use_bf16) {
    cg::grid_group grid = cg::this_grid();
    const int tid = blockIdx.x * blockDim.x + threadIdx.x;
    const int nthreads = gridDim.x * blockDim.x;

    // ---- P0: init (ws is poisoned 0xAA every call) ----
    for (int i = tid; i < n; i += nthreads) { head[i] = -1; deg[i] = 0; }
    __threadfence();
    grid.sync();

    // ---- P1: edge pass: out-degree hist + LIFO chain build ----
    // 1 random fire-forget atomic + 1 random atomic-with-return + 1 COALESCED 8B store.
    for (int e = tid; e < E; e += nthreads) {
        int s = src[e], t = dst[e];
        atomicAdd(&deg[s], 1);
        int prev = atomicExch(&head[t], e);
        pairs[e] = make_int2(s, prev);
    }
    __threadfence();
    grid.sync();

    // ---- P2: norm[] and yh = bf16(norm[i] * x[i,:]) (single rounding) ----
    for (int i = tid; i < n; i += nthreads)
        norm[i] = rsqrtf(fmaxf((float)deg[i], 1.0f));
    if (use_bf16) {
        const int total = n * (D / 2);               // uint (2 features) elements
        for (int i = tid; i < total; i += nthreads) {
            int node = i >> 5;                       // D/2 = 32 pairs per node
            float nm = rsqrtf(fmaxf((float)deg[node], 1.0f));  // recompute: no race w/ norm[]
            float2 v = ((const float2*)x)[i];
            yh[i] = f2bf(v.x * nm) | (f2bf(v.y * nm) << 16);
        }
    }
    __threadfence();
    grid.sync();

    // ---- P3: gather — 2 nodes per wave (32 lanes x ushort2/float2 = 64 features) ----
    const int lane = threadIdx.x & 63;
    const int half = lane >> 5;                      // which node of the pair
    const int fl   = lane & 31;                      // feature-pair index
    const int waveId    = tid >> 6;
    const int waveSlots = nthreads >> 6;
    for (int base = waveId * 2; base < n; base += waveSlots * 2) {
        int node = base + half;
        if (node >= n) continue;
        float2 acc = make_float2(0.0f, 0.0f);
        int cur = head[node];
        if (use_bf16) {
            while (cur >= 0) {
                int2 p = pairs[cur];                 // (src, next) — uniform per half-wave
                unsigned int v = yh[p.x * 32 + fl];  // 128B random row read
                acc.x += bf2f_lo(v);
                acc.y += bf2f_hi(v);
                cur = p.y;
            }
        } else {
            while (cur >= 0) {
                int2 p = pairs[cur];
                float nm = norm[p.x];
                float2 v = ((const float2*)x)[p.x * 32 + fl];
                acc.x += nm * v.x;
                acc.y += nm * v.y;
                cur = p.y;
            }
        }
        float nt = norm[node];
        float2 xv = ((const float2*)x)[node * 32 + fl];
        float2 r;
        r.x = acc.x * nt + EPS * xv.x;
        r.y = acc.y * nt + EPS * xv.y;
        ((float2*)out)[node * 32 + fl] = r;          // coalesced 256B per half-wave
    }
}

extern "C" void kernel_launch(void* const* d_in, const int* in_sizes, int n_in,
                              void* d_out, int out_size, void* d_ws, size_t ws_size,
                              hipStream_t stream) {
    const float* x   = (const float*)d_in[0];
    const int*   src = (const int*)d_in[1];
    const int*   dst = (const int*)d_in[2];
    float* out = (float*)d_out;

    const int ND = in_sizes[0];
    const int E  = in_sizes[1];
    const int n  = ND / D;

    // Workspace: pairs first (8B aligned at base), then int/float arrays, then yh.
    int2*  pairs = (int2*)d_ws;                       // E * 8B
    int*   head  = (int*)(pairs + E);                 // n
    int*   deg   = head + n;                          // n
    float* norm  = (float*)(deg + n);                 // n
    unsigned int* yh = (unsigned int*)(norm + n);     // ND/2 uints (bf16 pairs)

    size_t need_bf16 = (size_t)E * 8 + (size_t)3 * n * 4 + (size_t)(ND / 2) * 4;
    int use_bf16 = (need_bf16 <= ws_size) ? 1 : 0;    // fallback: gather f32 x directly

    const float* x_p = x; const int* src_p = src; const int* dst_p = dst;
    float* out_p = out; int2* pairs_p = pairs; int* head_p = head;
    int* deg_p = deg; float* norm_p = norm; unsigned int* yh_p = yh;
    int n_v = n, E_v = E, bf_v = use_bf16;

    void* args[] = { &x_p, &src_p, &dst_p, &out_p, &pairs_p, &head_p,
                     &deg_p, &norm_p, &yh_p, &n_v, &E_v, &bf_v };
    hipLaunchCooperativeKernel((const void*)gcn_fused, dim3(GRID), dim3(BLK),
                               args, 0, stream);
}

// Round 6
// 677.459 us; speedup vs baseline: 1.1744x; 1.1744x over previous
//
#include <hip/hip_runtime.h>

// GCN aggregation: out[t] = norm[t] * sum_{e:dst=t} norm[src]*x[src] + EPS*x[t]
// Round 6: bucket-partition pipeline (array adjacency — round-5's linked list was
// a serial pointer chase and regressed badly).
//   K_init      : zero deg, cursor[b]=b*CAPB, ovf_cnt=0
//   K_partition : ONE edge pass: fire-forget deg[src] atomic + LDS bucket histogram
//                 + one reserve atomic per (block,bucket) + record writes into
//                 per-bucket regions (semi-coalesced).
//   K_norm_y    : norm = rsqrt(max(deg,1)); yh = bf16(norm*x)  (single rounding)
//   K_accum     : one block per bucket; 128x64 f32 tile in LDS; waves stream
//                 records with 8-deep independent y-row loads; ds atomic add;
//                 coalesced epilogue fused with norm[t] and EPS*x residual.
//   K_cleanup   : rare bucket-overflow edges via float atomics (expected 0).
constexpr int D      = 64;
constexpr float EPS  = 0.5f;
constexpr int BKT    = 128;    // dst-nodes per bucket (LDS tile = 128*64*4 = 32 KB)
constexpr int CAPB   = 2048;   // records per bucket region (mean ~1598 at E/N=12.5, +11 sigma)
constexpr int EPB    = 4096;   // edges per partition block (16 per thread, kept in regs)
constexpr int NBMAX  = 1024;   // partition LDS arrays sized for NB <= 1024
constexpr int MAXOVF = 65536;

__device__ __forceinline__ unsigned int f2bf(float f) {
    unsigned int u = __float_as_uint(f);
    return (u + 0x7FFFu + ((u >> 16) & 1u)) >> 16;   // RNE to bf16
}
__device__ __forceinline__ float bf2f(unsigned short h) {
    return __uint_as_float(((unsigned int)h) << 16);
}

// ---------------- main path ----------------

__global__ void init_kernel(int* __restrict__ deg, int* __restrict__ cursor,
                            int* __restrict__ ovf_cnt, int n, int NB) {
    int i = blockIdx.x * blockDim.x + threadIdx.x;
    if (i < n) deg[i] = 0;
    if (i < NB) cursor[i] = i * CAPB;
    if (i == 0) *ovf_cnt = 0;
}

__global__ __launch_bounds__(256)
void partition_kernel(const int* __restrict__ src, const int* __restrict__ dst,
                      int* __restrict__ deg, int* __restrict__ cursor,
                      int2* __restrict__ rec, int* __restrict__ ovf_cnt,
                      int* __restrict__ ovf, int E, int NB) {
    __shared__ int hist[NBMAX];
    __shared__ int startb[NBMAX];
    __shared__ int rankb[NBMAX];
    const int base = blockIdx.x * EPB;
    const int tid  = threadIdx.x;
    for (int b = tid; b < NB; b += 256) { hist[b] = 0; rankb[b] = 0; }
    __syncthreads();

    int2 ed[EPB / 256];                       // 16 edges per thread, in registers
    #pragma unroll
    for (int k = 0; k < EPB / 256; ++k) {
        int e = base + tid + k * 256;         // coalesced
        if (e < E) {
            int s = src[e], t = dst[e];
            ed[k] = make_int2(s, t);
            atomicAdd(&deg[s], 1);            // fire-and-forget out-degree hist
            atomicAdd(&hist[t / BKT], 1);     // LDS bucket count
        }
    }
    __syncthreads();
    for (int b = tid; b < NB; b += 256) {     // one global atomic per (block,bucket)
        int c = hist[b];
        if (c > 0) startb[b] = atomicAdd(&cursor[b], c);
    }
    __syncthreads();
    #pragma unroll
    for (int k = 0; k < EPB / 256; ++k) {
        int e = base + tid + k * 256;
        if (e < E) {
            int b = ed[k].y / BKT;
            int r = atomicAdd(&rankb[b], 1);  // LDS rank
            int pos = startb[b] + r;
            if (pos < (b + 1) * CAPB) {
                rec[pos] = ed[k];             // semi-coalesced region store
            } else {
                int i = atomicAdd(ovf_cnt, 1);
                if (i < MAXOVF) { ovf[2 * i] = ed[k].x; ovf[2 * i + 1] = ed[k].y; }
            }
        }
    }
}

__global__ void norm_y_kernel(const float2* __restrict__ x2, const int* __restrict__ deg,
                              float* __restrict__ norm, unsigned int* __restrict__ yh, int n) {
    int i = blockIdx.x * blockDim.x + threadIdx.x;
    if (i < n) norm[i] = rsqrtf(fmaxf((float)deg[i], 1.0f));
    int total = n * (D / 2);
    for (int j = i; j < total; j += gridDim.x * blockDim.x) {
        int node = j >> 5;                                   // 32 pairs per node
        float nm = rsqrtf(fmaxf((float)deg[node], 1.0f));
        float2 v = x2[j];
        yh[j] = f2bf(v.x * nm) | (f2bf(v.y * nm) << 16);
    }
}

__global__ __launch_bounds__(256)
void accum_kernel(const unsigned short* __restrict__ yh, const float* __restrict__ x,
                  const int2* __restrict__ rec, const int* __restrict__ cursor,
                  const float* __restrict__ norm, float* __restrict__ out, int n) {
    __shared__ float acc[BKT * D];                            // 32 KB
    const int b   = blockIdx.x;
    const int tid = threadIdx.x;
    float4* a4 = (float4*)acc;
    for (int i = tid; i < BKT * D / 4; i += 256) a4[i] = make_float4(0.f, 0.f, 0.f, 0.f);
    __syncthreads();

    int cnt = cursor[b] - b * CAPB;
    if (cnt > CAPB) cnt = CAPB;
    const int2* r0 = rec + (size_t)b * CAPB;
    const int lane = tid & 63;
    const int w    = tid >> 6;                                // wave 0..3

    // wave w owns index chunks [w*8 + m*32, +8): 8 independent y-row loads in flight
    int i = w * 8;
    for (; i + 8 <= cnt; i += 32) {
        int2 p0 = r0[i + 0], p1 = r0[i + 1], p2 = r0[i + 2], p3 = r0[i + 3];
        int2 p4 = r0[i + 4], p5 = r0[i + 5], p6 = r0[i + 6], p7 = r0[i + 7];
        float v0 = bf2f(yh[(size_t)p0.x * D + lane]);
        float v1 = bf2f(yh[(size_t)p1.x * D + lane]);
        float v2 = bf2f(yh[(size_t)p2.x * D + lane]);
        float v3 = bf2f(yh[(size_t)p3.x * D + lane]);
        float v4 = bf2f(yh[(size_t)p4.x * D + lane]);
        float v5 = bf2f(yh[(size_t)p5.x * D + lane]);
        float v6 = bf2f(yh[(size_t)p6.x * D + lane]);
        float v7 = bf2f(yh[(size_t)p7.x * D + lane]);
        atomicAdd(&acc[((p0.y & (BKT - 1)) << 6) + lane], v0);
        atomicAdd(&acc[((p1.y & (BKT - 1)) << 6) + lane], v1);
        atomicAdd(&acc[((p2.y & (BKT - 1)) << 6) + lane], v2);
        atomicAdd(&acc[((p3.y & (BKT - 1)) << 6) + lane], v3);
        atomicAdd(&acc[((p4.y & (BKT - 1)) << 6) + lane], v4);
        atomicAdd(&acc[((p5.y & (BKT - 1)) << 6) + lane], v5);
        atomicAdd(&acc[((p6.y & (BKT - 1)) << 6) + lane], v6);
        atomicAdd(&acc[((p7.y & (BKT - 1)) << 6) + lane], v7);
    }
    for (int j = i; j < cnt && j < i + 8; ++j) {              // wave's final partial chunk
        int2 p = r0[j];
        float v = bf2f(yh[(size_t)p.x * D + lane]);
        atomicAdd(&acc[((p.y & (BKT - 1)) << 6) + lane], v);
    }
    __syncthreads();

    int nodes = n - b * BKT; if (nodes > BKT) nodes = BKT;
    int totalf = nodes * D;
    size_t gbase = (size_t)b * BKT * D;
    for (int idx = tid; idx < totalf; idx += 256) {           // coalesced epilogue
        int t = b * BKT + (idx >> 6);
        out[gbase + idx] = acc[idx] * norm[t] + EPS * x[gbase + idx];
    }
}

__global__ void cleanup_kernel(const float* __restrict__ x, const float* __restrict__ norm,
                               const int* __restrict__ ovf_cnt, const int* __restrict__ ovf,
                               float* __restrict__ out) {
    int cnt = *ovf_cnt;
    if (cnt > MAXOVF) cnt = MAXOVF;
    long long total = (long long)cnt * D;
    long long stride = (long long)gridDim.x * blockDim.x;
    for (long long i = blockIdx.x * (long long)blockDim.x + threadIdx.x; i < total; i += stride) {
        int e = (int)(i >> 6), d = (int)(i & 63);
        int s = ovf[2 * e], t = ovf[2 * e + 1];
        atomicAdd(&out[(size_t)t * D + d], norm[s] * norm[t] * x[(size_t)s * D + d]);
    }
}

// ---------------- fallback (tiny ws): round-1 style atomic scatter ----------------

__global__ void fb_hist(const int* __restrict__ src, int* __restrict__ deg, int E) {
    int e = blockIdx.x * blockDim.x + threadIdx.x;
    if (e < E) atomicAdd(&deg[src[e]], 1);
}
__global__ void fb_norm(const int* __restrict__ deg, float* __restrict__ norm, int n) {
    int i = blockIdx.x * blockDim.x + threadIdx.x;
    if (i < n) norm[i] = rsqrtf(fmaxf((float)deg[i], 1.0f));
}
__global__ void fb_init_out(const float4* __restrict__ x, float4* __restrict__ out, int n4) {
    int i = blockIdx.x * blockDim.x + threadIdx.x;
    if (i < n4) {
        float4 v = x[i];
        out[i] = make_float4(v.x * EPS, v.y * EPS, v.z * EPS, v.w * EPS);
    }
}
__global__ void fb_scatter(const float* __restrict__ x, const int* __restrict__ src,
                           const int* __restrict__ dst, const float* __restrict__ norm,
                           float* __restrict__ out, int E) {
    long long tid = (long long)blockIdx.x * blockDim.x + threadIdx.x;
    int e = (int)(tid >> 6), d = (int)(tid & 63);
    if (e < E) {
        int s = src[e], t = dst[e];
        atomicAdd(&out[(size_t)t * D + d], norm[s] * norm[t] * x[(size_t)s * D + d]);
    }
}

// ---------------- launcher ----------------

extern "C" void kernel_launch(void* const* d_in, const int* in_sizes, int n_in,
                              void* d_out, int out_size, void* d_ws, size_t ws_size,
                              hipStream_t stream) {
    const float* x   = (const float*)d_in[0];
    const int*   src = (const int*)d_in[1];
    const int*   dst = (const int*)d_in[2];
    float* out = (float*)d_out;

    const int ND = in_sizes[0];
    const int E  = in_sizes[1];
    const int n  = ND / D;
    const int NB = (n + BKT - 1) / BKT;
    constexpr int B = 256;

    // Workspace layout: rec | cursor | deg | norm | yh | ovf_cnt(pad 64) | ovf
    size_t need = (size_t)NB * CAPB * 8 + ((size_t)NB + 64) * 4
                + (size_t)n * 4 * 2 + (size_t)(ND / 2) * 4
                + (size_t)(2 * MAXOVF + 64) * 4;

    if (NB <= NBMAX && need <= ws_size) {
        int2*  rec     = (int2*)d_ws;                       // NB*CAPB records
        int*   cursor  = (int*)(rec + (size_t)NB * CAPB);   // NB (+pad to 64)
        int*   deg     = cursor + ((NB + 63) & ~63);        // n
        float* norm    = (float*)(deg + n);                 // n
        unsigned int* yh = (unsigned int*)(norm + n);       // ND/2 uints (bf16 pairs)
        int*   ovf_cnt = (int*)(yh + ND / 2);               // 64 (pad; [0] used)
        int*   ovf     = ovf_cnt + 64;                      // 2*MAXOVF

        int initN = (n > NB ? n : NB);
        init_kernel<<<(initN + B - 1) / B, B, 0, stream>>>(deg, cursor, ovf_cnt, n, NB);
        partition_kernel<<<(E + EPB - 1) / EPB, B, 0, stream>>>(src, dst, deg, cursor,
                                                                rec, ovf_cnt, ovf, E, NB);
        norm_y_kernel<<<(n * (D / 2) + B - 1) / B, B, 0, stream>>>((const float2*)x, deg,
                                                                   norm, yh, n);
        accum_kernel<<<NB, B, 0, stream>>>((const unsigned short*)yh, x, rec, cursor,
                                           norm, out, n);
        cleanup_kernel<<<64, B, 0, stream>>>(x, norm, ovf_cnt, ovf, out);
    } else {
        // tiny-ws fallback: deg hist + norm + atomic scatter
        int*   deg  = (int*)d_ws;
        float* norm = (float*)d_ws + n;
        hipMemsetAsync(deg, 0, (size_t)n * sizeof(int), stream);
        fb_hist<<<(E + B - 1) / B, B, 0, stream>>>(src, deg, E);
        fb_norm<<<(n + B - 1) / B, B, 0, stream>>>(deg, norm, n);
        fb_init_out<<<(ND / 4 + B - 1) / B, B, 0, stream>>>((const float4*)x, (float4*)out, ND / 4);
        long long total = (long long)E * D;
        fb_scatter<<<(int)((total + B - 1) / B), B, 0, stream>>>(x, src, dst, norm, out, E);
    }
}

// Round 7
// 205.869 us; speedup vs baseline: 3.8648x; 3.2907x over previous
//
#include <hip/hip_runtime.h>

// GCN aggregation: out[t] = norm[t] * sum_{e:dst=t} norm[src]*x[src] + EPS*x[t]
// Round 7: keep the proven wave-per-node gather (at the random-row-read floor);
// replace the fused_fill (2.5M random atomics + 1.25M random stores, 126us) with:
//   partition  : LDS bucket hist + ONE reserve atomic per (block,bucket) + semi-
//                coalesced region stores (+ fire-forget deg[src] atomic) [worked in R6]
//   sort       : per-bucket LDS counting sort -> exact per-node CSR + row_start/cnt
// yh = bf16(norm[src]*x[src]) (single rounding) so gather needs no per-edge norm.
constexpr int D      = 64;
constexpr float EPS  = 0.5f;
constexpr int BKT    = 128;     // dst-nodes per bucket
constexpr int CAPB_MAX = 2048;  // max records per bucket region (LDS sort sized for this)
constexpr int EPB    = 4096;    // edges per partition block (16/thread in regs)
constexpr int NBMAX  = 1024;
constexpr int MAXOVF = 65536;

__device__ __forceinline__ unsigned int f2bf(float f) {
    unsigned int u = __float_as_uint(f);
    return (u + 0x7FFFu + ((u >> 16) & 1u)) >> 16;   // RNE to bf16
}
__device__ __forceinline__ float bf2f(unsigned short h) {
    return __uint_as_float(((unsigned int)h) << 16);
}

// ---------------- main path ----------------

__global__ void init_kernel(int* __restrict__ deg, int* __restrict__ cursor,
                            int* __restrict__ ovf_cnt, int n, int NB, int capb) {
    int i = blockIdx.x * blockDim.x + threadIdx.x;
    if (i < n) deg[i] = 0;
    if (i < NB) cursor[i] = i * capb;
    if (i == 0) *ovf_cnt = 0;
}

__global__ __launch_bounds__(256)
void partition_kernel(const int* __restrict__ src, const int* __restrict__ dst,
                      int* __restrict__ deg, int* __restrict__ cursor,
                      int2* __restrict__ rec, int* __restrict__ ovf_cnt,
                      int* __restrict__ ovf, int E, int NB, int capb) {
    __shared__ int hist[NBMAX];
    __shared__ int startb[NBMAX];
    __shared__ int rankb[NBMAX];
    const int base = blockIdx.x * EPB;
    const int tid  = threadIdx.x;
    for (int b = tid; b < NB; b += 256) { hist[b] = 0; rankb[b] = 0; }
    __syncthreads();

    int2 ed[EPB / 256];                       // 16 edges/thread in registers
    #pragma unroll
    for (int k = 0; k < EPB / 256; ++k) {
        int e = base + tid + k * 256;         // coalesced
        if (e < E) {
            int s = src[e], t = dst[e];
            ed[k] = make_int2(s, t);
            atomicAdd(&deg[s], 1);            // fire-and-forget out-degree hist
            atomicAdd(&hist[t >> 7], 1);      // LDS bucket count (BKT=128)
        }
    }
    __syncthreads();
    for (int b = tid; b < NB; b += 256) {     // one global atomic per (block,bucket)
        int c = hist[b];
        if (c > 0) startb[b] = atomicAdd(&cursor[b], c);
    }
    __syncthreads();
    #pragma unroll
    for (int k = 0; k < EPB / 256; ++k) {
        int e = base + tid + k * 256;
        if (e < E) {
            int b = ed[k].y >> 7;
            int r = atomicAdd(&rankb[b], 1);  // LDS rank
            int pos = startb[b] + r;
            if (pos < (b + 1) * capb) {
                rec[pos] = ed[k];             // semi-coalesced region store
            } else {
                int i = atomicAdd(ovf_cnt, 1);
                if (i < MAXOVF) { ovf[2 * i] = ed[k].x; ovf[2 * i + 1] = ed[k].y; }
            }
        }
    }
}

// norm = rsqrt(max(deg,1)); yh = bf16(norm * x) — single rounding, norm folded in
__global__ void norm_y_kernel(const float2* __restrict__ x2, const int* __restrict__ deg,
                              float* __restrict__ norm, unsigned int* __restrict__ yh, int n) {
    int i = blockIdx.x * blockDim.x + threadIdx.x;
    if (i < n) norm[i] = rsqrtf(fmaxf((float)deg[i], 1.0f));
    int total = n * (D / 2);
    for (int j = i; j < total; j += gridDim.x * blockDim.x) {
        int node = j >> 5;                                   // 32 float2 per node
        float nm = rsqrtf(fmaxf((float)deg[node], 1.0f));
        float2 v = x2[j];
        yh[j] = f2bf(v.x * nm) | (f2bf(v.y * nm) << 16);
    }
}

// Per-bucket LDS counting sort: rec region -> per-node-ordered csr + row_start/cnt.
__global__ __launch_bounds__(256)
void sort_kernel(const int2* __restrict__ rec, const int* __restrict__ cursor,
                 int* __restrict__ csr, int* __restrict__ row_start,
                 int* __restrict__ row_cnt, int n, int capb) {
    __shared__ int2 recs[CAPB_MAX];       // 16 KB
    __shared__ int  srcs[CAPB_MAX];       // 8 KB
    __shared__ int  hist[BKT];
    __shared__ int  scanv[BKT];
    __shared__ int  rankb[BKT];
    const int b   = blockIdx.x;
    const int tid = threadIdx.x;
    int cnt = cursor[b] - b * capb;
    if (cnt > capb) cnt = capb;

    for (int i = tid; i < cnt; i += 256) recs[i] = rec[(size_t)b * capb + i];
    if (tid < BKT) hist[tid] = 0;
    __syncthreads();
    for (int i = tid; i < cnt; i += 256) atomicAdd(&hist[recs[i].y & (BKT - 1)], 1);
    __syncthreads();
    if (tid < BKT) scanv[tid] = hist[tid];
    __syncthreads();
    #pragma unroll
    for (int off = 1; off < BKT; off <<= 1) {        // Hillis-Steele inclusive scan
        int t = 0;
        if (tid < BKT && tid >= off) t = scanv[tid - off];
        __syncthreads();
        if (tid < BKT) scanv[tid] += t;
        __syncthreads();
    }
    if (tid < BKT) {
        int excl = scanv[tid] - hist[tid];
        rankb[tid] = excl;
        int node = b * BKT + tid;
        if (node < n) {
            row_start[node] = b * capb + excl;
            row_cnt[node]   = hist[tid];
        }
    }
    __syncthreads();
    for (int i = tid; i < cnt; i += 256) {
        int pos = atomicAdd(&rankb[recs[i].y & (BKT - 1)], 1);
        srcs[pos] = recs[i].x;
    }
    __syncthreads();
    for (int i = tid; i < cnt; i += 256) csr[(size_t)b * capb + i] = srcs[i];
}

// One wave per node, lane = feature. yh rows already carry norm[src].
__global__ __launch_bounds__(256)
void gather_kernel(const unsigned short* __restrict__ yh, const float* __restrict__ x,
                   const int* __restrict__ csr, const int* __restrict__ row_start,
                   const int* __restrict__ row_cnt, const float* __restrict__ norm,
                   float* __restrict__ out, int n) {
    int node = blockIdx.x * (blockDim.x >> 6) + (threadIdx.x >> 6);
    int lane = threadIdx.x & 63;
    if (node >= n) return;
    const int* row = csr + row_start[node];
    int cnt = row_cnt[node];
    float acc = 0.0f;
    int k = 0;
    for (; k + 8 <= cnt; k += 8) {
        int s0 = row[k], s1 = row[k+1], s2 = row[k+2], s3 = row[k+3];
        int s4 = row[k+4], s5 = row[k+5], s6 = row[k+6], s7 = row[k+7];
        float v0 = bf2f(yh[(size_t)s0 * D + lane]);
        float v1 = bf2f(yh[(size_t)s1 * D + lane]);
        float v2 = bf2f(yh[(size_t)s2 * D + lane]);
        float v3 = bf2f(yh[(size_t)s3 * D + lane]);
        float v4 = bf2f(yh[(size_t)s4 * D + lane]);
        float v5 = bf2f(yh[(size_t)s5 * D + lane]);
        float v6 = bf2f(yh[(size_t)s6 * D + lane]);
        float v7 = bf2f(yh[(size_t)s7 * D + lane]);
        acc += ((v0 + v1) + (v2 + v3)) + ((v4 + v5) + (v6 + v7));
    }
    for (; k + 4 <= cnt; k += 4) {
        int s0 = row[k], s1 = row[k+1], s2 = row[k+2], s3 = row[k+3];
        float v0 = bf2f(yh[(size_t)s0 * D + lane]);
        float v1 = bf2f(yh[(size_t)s1 * D + lane]);
        float v2 = bf2f(yh[(size_t)s2 * D + lane]);
        float v3 = bf2f(yh[(size_t)s3 * D + lane]);
        acc += (v0 + v1) + (v2 + v3);
    }
    for (; k < cnt; ++k) acc += bf2f(yh[(size_t)row[k] * D + lane]);
    out[(size_t)node * D + lane] = acc * norm[node] + EPS * x[(size_t)node * D + lane];
}

__global__ void cleanup_kernel(const float* __restrict__ x, const float* __restrict__ norm,
                               const int* __restrict__ ovf_cnt, const int* __restrict__ ovf,
                               float* __restrict__ out) {
    int cnt = *ovf_cnt;
    if (cnt > MAXOVF) cnt = MAXOVF;
    long long total = (long long)cnt * D;
    long long stride = (long long)gridDim.x * blockDim.x;
    for (long long i = blockIdx.x * (long long)blockDim.x + threadIdx.x; i < total; i += stride) {
        int e = (int)(i >> 6), d = (int)(i & 63);
        int s = ovf[2 * e], t = ovf[2 * e + 1];
        atomicAdd(&out[(size_t)t * D + d], norm[s] * norm[t] * x[(size_t)s * D + d]);
    }
}

// ---------------- tiny-ws fallback (round-1 proven) ----------------

__global__ void fb_hist(const int* __restrict__ src, int* __restrict__ deg, int E) {
    int e = blockIdx.x * blockDim.x + threadIdx.x;
    if (e < E) atomicAdd(&deg[src[e]], 1);
}
__global__ void fb_norm(const int* __restrict__ deg, float* __restrict__ norm, int n) {
    int i = blockIdx.x * blockDim.x + threadIdx.x;
    if (i < n) norm[i] = rsqrtf(fmaxf((float)deg[i], 1.0f));
}
__global__ void fb_init_out(const float4* __restrict__ x, float4* __restrict__ out, int n4) {
    int i = blockIdx.x * blockDim.x + threadIdx.x;
    if (i < n4) {
        float4 v = x[i];
        out[i] = make_float4(v.x * EPS, v.y * EPS, v.z * EPS, v.w * EPS);
    }
}
__global__ void fb_scatter(const float* __restrict__ x, const int* __restrict__ src,
                           const int* __restrict__ dst, const float* __restrict__ norm,
                           float* __restrict__ out, int E) {
    long long tid = (long long)blockIdx.x * blockDim.x + threadIdx.x;
    int e = (int)(tid >> 6), d = (int)(tid & 63);
    if (e < E) {
        int s = src[e], t = dst[e];
        atomicAdd(&out[(size_t)t * D + d], norm[s] * norm[t] * x[(size_t)s * D + d]);
    }
}

// ---------------- launcher ----------------

extern "C" void kernel_launch(void* const* d_in, const int* in_sizes, int n_in,
                              void* d_out, int out_size, void* d_ws, size_t ws_size,
                              hipStream_t stream) {
    const float* x   = (const float*)d_in[0];
    const int*   src = (const int*)d_in[1];
    const int*   dst = (const int*)d_in[2];
    float* out = (float*)d_out;

    const int ND = in_sizes[0];
    const int E  = in_sizes[1];
    const int n  = ND / D;
    const int NB = (n + BKT - 1) / BKT;
    constexpr int B = 256;

    // Pick bucket capacity that fits ws (mean E/NB ~1598 here; 2048 = +11 sigma,
    // 1792 = +4.8 sigma with overflow absorbed by cleanup).
    int capb = 0;
    for (int c : {2048, 1792}) {
        size_t need = (size_t)NB * c * 8            // rec
                    + (size_t)NB * c * 4            // csr
                    + ((size_t)(NB + 63) & ~63ull) * 4
                    + (size_t)n * 4 * 4             // deg, norm, row_start, row_cnt
                    + (size_t)ND * 2                // yh
                    + (size_t)(64 + 2 * MAXOVF) * 4;
        if (need <= ws_size) { capb = c; break; }
    }

    if (NB <= NBMAX && capb > 0) {
        int2*  rec       = (int2*)d_ws;                        // NB*capb
        int*   csr       = (int*)(rec + (size_t)NB * capb);    // NB*capb
        int*   cursor    = csr + (size_t)NB * capb;            // NB (pad 64)
        int*   deg       = cursor + ((NB + 63) & ~63);         // n
        float* norm      = (float*)(deg + n);                  // n
        int*   row_start = (int*)(norm + n);                   // n
        int*   row_cnt   = row_start + n;                      // n
        unsigned int* yh = (unsigned int*)(row_cnt + n);       // ND/2 uints
        int*   ovf_cnt   = (int*)(yh + ND / 2);                // 64 (pad; [0] used)
        int*   ovf       = ovf_cnt + 64;                       // 2*MAXOVF

        int initN = (n > NB ? n : NB);
        init_kernel<<<(initN + B - 1) / B, B, 0, stream>>>(deg, cursor, ovf_cnt, n, NB, capb);
        partition_kernel<<<(E + EPB - 1) / EPB, B, 0, stream>>>(src, dst, deg, cursor,
                                                                rec, ovf_cnt, ovf, E, NB, capb);
        norm_y_kernel<<<(n * (D / 2) + B - 1) / B, B, 0, stream>>>((const float2*)x, deg,
                                                                   norm, yh, n);
        sort_kernel<<<NB, B, 0, stream>>>(rec, cursor, csr, row_start, row_cnt, n, capb);
        gather_kernel<<<(n + 3) / 4, B, 0, stream>>>((const unsigned short*)yh, x, csr,
                                                     row_start, row_cnt, norm, out, n);
        cleanup_kernel<<<64, B, 0, stream>>>(x, norm, ovf_cnt, ovf, out);
    } else {
        int*   deg  = (int*)d_ws;
        float* norm = (float*)d_ws + n;
        hipMemsetAsync(deg, 0, (size_t)n * sizeof(int), stream);
        fb_hist<<<(E + B - 1) / B, B, 0, stream>>>(src, deg, E);
        fb_norm<<<(n + B - 1) / B, B, 0, stream>>>(deg, norm, n);
        fb_init_out<<<(ND / 4 + B - 1) / B, B, 0, stream>>>((const float4*)x, (float4*)out, ND / 4);
        long long total = (long long)E * D;
        fb_scatter<<<(int)((total + B - 1) / B), B, 0, stream>>>(x, src, dst, norm, out, E);
    }
}

// Round 8
// 180.091 us; speedup vs baseline: 4.4180x; 1.1431x over previous
//
#include <hip/hip_runtime.h>

// GCN aggregation: out[t] = norm[t] * sum_{e:dst=t} norm[src]*x[src] + EPS*x[t]
// Round 8: (a) dual-bucket partition — dst records (packed 4B: s<<7|t&127) for the
// CSR, plus src-bucket uchar records so out-degree comes from per-bucket LDS counts
// with PLAIN stores (kills 1.25M random deg atomics = ~40MB of 32B sectors);
// (b) gather processes 4 nodes/wave (quarter-wave x ushort4 = 128B row each),
// ~3x fewer row-load instructions; uniform loop to wave-max(cnt) avoids divergence.
constexpr int D        = 64;
constexpr float EPS    = 0.5f;
constexpr int BKT      = 128;
constexpr int CAPB_MAX = 2048;
constexpr int EPB      = 4096;   // edges per partition block
constexpr int NBMAX    = 1024;
constexpr int MAXOVF   = 65536;

__device__ __forceinline__ unsigned int f2bf(float f) {
    unsigned int u = __float_as_uint(f);
    return (u + 0x7FFFu + ((u >> 16) & 1u)) >> 16;   // RNE to bf16
}
__device__ __forceinline__ float bf2f_lo(unsigned int v) { return __uint_as_float(v << 16); }
__device__ __forceinline__ float bf2f_hi(unsigned int v) { return __uint_as_float(v & 0xFFFF0000u); }

// ---------------- main path ----------------

__global__ void init_kernel(int* __restrict__ curD, int* __restrict__ curS,
                            int* __restrict__ ovf_cnt, int* __restrict__ sovf_cnt,
                            int NB, int capb) {
    int i = blockIdx.x * blockDim.x + threadIdx.x;
    if (i < NB) { curD[i] = i * capb; curS[i] = i * capb; }
    if (i == 0) { *ovf_cnt = 0; *sovf_cnt = 0; }
}

__global__ __launch_bounds__(256)
void partition_kernel(const int* __restrict__ src, const int* __restrict__ dst,
                      int* __restrict__ curD, int* __restrict__ curS,
                      unsigned int* __restrict__ rec, unsigned char* __restrict__ srec,
                      int* __restrict__ ovf_cnt, int* __restrict__ ovf,
                      int* __restrict__ sovf_cnt, int* __restrict__ sovf,
                      int E, int NB, int capb) {
    __shared__ int histD[NBMAX];   // then reused as rankD
    __shared__ int histS[NBMAX];   // then reused as rankS
    __shared__ int startD[NBMAX];
    __shared__ int startS[NBMAX];
    const int base = blockIdx.x * EPB;
    const int tid  = threadIdx.x;
    for (int b = tid; b < NB; b += 256) { histD[b] = 0; histS[b] = 0; }
    __syncthreads();

    #pragma unroll
    for (int k = 0; k < EPB / 256; ++k) {
        int e = base + tid + k * 256;          // coalesced
        if (e < E) {
            atomicAdd(&histD[dst[e] >> 7], 1);
            atomicAdd(&histS[src[e] >> 7], 1);
        }
    }
    __syncthreads();
    for (int b = tid; b < NB; b += 256) {      // one global reserve atomic per (block,bucket)
        int c = histD[b];
        startD[b] = (c > 0) ? atomicAdd(&curD[b], c) : 0;
        histD[b] = 0;                          // reuse as rank
        int c2 = histS[b];
        startS[b] = (c2 > 0) ? atomicAdd(&curS[b], c2) : 0;
        histS[b] = 0;
    }
    __syncthreads();
    #pragma unroll
    for (int k = 0; k < EPB / 256; ++k) {
        int e = base + tid + k * 256;
        if (e < E) {
            int s = src[e], t = dst[e];
            int bD = t >> 7;
            int r  = atomicAdd(&histD[bD], 1);
            int pD = startD[bD] + r;
            if (pD < (bD + 1) * capb) {
                rec[pD] = ((unsigned int)s << 7) | (unsigned int)(t & (BKT - 1));
            } else {
                int i = atomicAdd(ovf_cnt, 1);
                if (i < MAXOVF) { ovf[2 * i] = s; ovf[2 * i + 1] = t; }
            }
            int bS = s >> 7;
            int r2 = atomicAdd(&histS[bS], 1);
            int pS = startS[bS] + r2;
            if (pS < (bS + 1) * capb) {
                srec[pS] = (unsigned char)(s & (BKT - 1));
            } else {
                int i = atomicAdd(sovf_cnt, 1);
                if (i < MAXOVF) sovf[i] = s;
            }
        }
    }
}

// grid = 2*NB: first NB blocks sort dst-regions into per-node CSR;
// last NB blocks count src-regions -> deg[] via plain stores.
__global__ __launch_bounds__(256)
void combo_kernel(const unsigned int* __restrict__ rec, const unsigned char* __restrict__ srec,
                  const int* __restrict__ curD, const int* __restrict__ curS,
                  int* __restrict__ csr, int* __restrict__ row_start,
                  int* __restrict__ row_cnt, int* __restrict__ deg, int n, int NB, int capb) {
    __shared__ unsigned int recs[CAPB_MAX];   // 8 KB
    __shared__ int srcs[CAPB_MAX];            // 8 KB
    __shared__ int hist[BKT];
    __shared__ int scanv[BKT];
    __shared__ int rankb[BKT];
    const int tid = threadIdx.x;

    if (blockIdx.x >= NB) {
        // ---- degcount path ----
        int b = blockIdx.x - NB;
        int cnt = curS[b] - b * capb;
        if (cnt > capb) cnt = capb;
        if (tid < BKT) hist[tid] = 0;
        __syncthreads();
        for (int i = tid; i < cnt; i += 256)
            atomicAdd(&hist[srec[(size_t)b * capb + i]], 1);
        __syncthreads();
        if (tid < BKT) {
            int node = b * BKT + tid;
            if (node < n) deg[node] = hist[tid];   // plain store — no global atomics
        }
        return;
    }

    // ---- sort path ----
    const int b = blockIdx.x;
    int cnt = curD[b] - b * capb;
    if (cnt > capb) cnt = capb;
    for (int i = tid; i < cnt; i += 256) recs[i] = rec[(size_t)b * capb + i];
    if (tid < BKT) hist[tid] = 0;
    __syncthreads();
    for (int i = tid; i < cnt; i += 256) atomicAdd(&hist[recs[i] & (BKT - 1)], 1);
    __syncthreads();
    if (tid < BKT) scanv[tid] = hist[tid];
    __syncthreads();
    #pragma unroll
    for (int off = 1; off < BKT; off <<= 1) {          // Hillis-Steele inclusive scan
        int t = 0;
        if (tid < BKT && tid >= off) t = scanv[tid - off];
        __syncthreads();
        if (tid < BKT) scanv[tid] += t;
        __syncthreads();
    }
    if (tid < BKT) {
        int excl = scanv[tid] - hist[tid];
        rankb[tid] = excl;
        int node = b * BKT + tid;
        if (node < n) {
            row_start[node] = b * capb + excl;
            row_cnt[node]   = hist[tid];
        }
    }
    __syncthreads();
    for (int i = tid; i < cnt; i += 256) {
        unsigned int v = recs[i];
        int pos = atomicAdd(&rankb[v & (BKT - 1)], 1);
        srcs[pos] = (int)(v >> 7);
    }
    __syncthreads();
    for (int i = tid; i < cnt; i += 256) csr[(size_t)b * capb + i] = srcs[i];
}

// rare: src-bucket overflow entries (expected 0)
__global__ void spill_kernel(const int* __restrict__ sovf_cnt, const int* __restrict__ sovf,
                             int* __restrict__ deg) {
    int cnt = *sovf_cnt;
    if (cnt > MAXOVF) cnt = MAXOVF;
    for (int i = blockIdx.x * blockDim.x + threadIdx.x; i < cnt; i += gridDim.x * blockDim.x)
        atomicAdd(&deg[sovf[i]], 1);
}

// norm = rsqrt(max(deg,1)); yh = bf16(norm*x) — single rounding, norm folded in
__global__ void norm_y_kernel(const float2* __restrict__ x2, const int* __restrict__ deg,
                              float* __restrict__ norm, unsigned int* __restrict__ yh, int n) {
    int i = blockIdx.x * blockDim.x + threadIdx.x;
    if (i < n) norm[i] = rsqrtf(fmaxf((float)deg[i], 1.0f));
    int total = n * (D / 2);
    for (int j = i; j < total; j += gridDim.x * blockDim.x) {
        int node = j >> 5;
        float nm = rsqrtf(fmaxf((float)deg[node], 1.0f));
        float2 v = x2[j];
        yh[j] = f2bf(v.x * nm) | (f2bf(v.y * nm) << 16);
    }
}

// 4 nodes per wave: quarter (16 lanes) x ushort4 = one 128B yh row per quarter.
// Uniform loop count = wave-max(cnt); out-of-range iterations masked to zero.
__global__ __launch_bounds__(256)
void gather4_kernel(const uint2* __restrict__ yr, const float4* __restrict__ x4,
                    const int* __restrict__ csr, const int* __restrict__ row_start,
                    const int* __restrict__ row_cnt, const float* __restrict__ norm,
                    float4* __restrict__ out4, int n) {
    int wid  = (blockIdx.x * blockDim.x + threadIdx.x) >> 6;
    int lane = threadIdx.x & 63;
    int q    = lane >> 4;          // quarter 0..3
    int fl   = lane & 15;          // float4 index within row
    int node = wid * 4 + q;
    bool valid = node < n;
    int rs  = valid ? row_start[node] : 0;
    int cnt = valid ? row_cnt[node] : 0;
    int m = cnt;
    m = max(m, __shfl_xor(m, 16));
    m = max(m, __shfl_xor(m, 32));
    float4 acc = make_float4(0.f, 0.f, 0.f, 0.f);
    for (int k = 0; k < m; k += 4) {
        #pragma unroll
        for (int j = 0; j < 4; ++j) {
            int kj = k + j;
            bool take = kj < cnt;
            int kk = take ? kj : 0;
            int s = csr[rs + kk];
            s = take ? s : 0;
            uint2 v = yr[(size_t)s * 16 + fl];
            v.x = take ? v.x : 0u;
            v.y = take ? v.y : 0u;
            acc.x += bf2f_lo(v.x);  acc.y += bf2f_hi(v.x);
            acc.z += bf2f_lo(v.y);  acc.w += bf2f_hi(v.y);
        }
    }
    if (valid) {
        float nt = norm[node];
        float4 xv = x4[(size_t)node * 16 + fl];
        float4 r;
        r.x = acc.x * nt + EPS * xv.x;
        r.y = acc.y * nt + EPS * xv.y;
        r.z = acc.z * nt + EPS * xv.z;
        r.w = acc.w * nt + EPS * xv.w;
        out4[(size_t)node * 16 + fl] = r;      // fully coalesced 16B/lane
    }
}

// rare: dst-bucket overflow edges (expected 0)
__global__ void cleanup_kernel(const float* __restrict__ x, const float* __restrict__ norm,
                               const int* __restrict__ ovf_cnt, const int* __restrict__ ovf,
                               float* __restrict__ out) {
    int cnt = *ovf_cnt;
    if (cnt > MAXOVF) cnt = MAXOVF;
    long long total = (long long)cnt * D;
    long long stride = (long long)gridDim.x * blockDim.x;
    for (long long i = blockIdx.x * (long long)blockDim.x + threadIdx.x; i < total; i += stride) {
        int e = (int)(i >> 6), d = (int)(i & 63);
        int s = ovf[2 * e], t = ovf[2 * e + 1];
        atomicAdd(&out[(size_t)t * D + d], norm[s] * norm[t] * x[(size_t)s * D + d]);
    }
}

// ---------------- tiny-ws / big-n fallback (round-1 proven) ----------------

__global__ void fb_hist(const int* __restrict__ src, int* __restrict__ deg, int E) {
    int e = blockIdx.x * blockDim.x + threadIdx.x;
    if (e < E) atomicAdd(&deg[src[e]], 1);
}
__global__ void fb_norm(const int* __restrict__ deg, float* __restrict__ norm, int n) {
    int i = blockIdx.x * blockDim.x + threadIdx.x;
    if (i < n) norm[i] = rsqrtf(fmaxf((float)deg[i], 1.0f));
}
__global__ void fb_init_out(const float4* __restrict__ x, float4* __restrict__ out, int n4) {
    int i = blockIdx.x * blockDim.x + threadIdx.x;
    if (i < n4) {
        float4 v = x[i];
        out[i] = make_float4(v.x * EPS, v.y * EPS, v.z * EPS, v.w * EPS);
    }
}
__global__ void fb_scatter(const float* __restrict__ x, const int* __restrict__ src,
                           const int* __restrict__ dst, const float* __restrict__ norm,
                           float* __restrict__ out, int E) {
    long long tid = (long long)blockIdx.x * blockDim.x + threadIdx.x;
    int e = (int)(tid >> 6), d = (int)(tid & 63);
    if (e < E) {
        int s = src[e], t = dst[e];
        atomicAdd(&out[(size_t)t * D + d], norm[s] * norm[t] * x[(size_t)s * D + d]);
    }
}

// ---------------- launcher ----------------

extern "C" void kernel_launch(void* const* d_in, const int* in_sizes, int n_in,
                              void* d_out, int out_size, void* d_ws, size_t ws_size,
                              hipStream_t stream) {
    const float* x   = (const float*)d_in[0];
    const int*   src = (const int*)d_in[1];
    const int*   dst = (const int*)d_in[2];
    float* out = (float*)d_out;

    const int ND = in_sizes[0];
    const int E  = in_sizes[1];
    const int n  = ND / D;
    const int NB = (n + BKT - 1) / BKT;
    constexpr int B = 256;

    int capb = 0;
    for (int c : {2048, 1792}) {
        size_t need = (size_t)NB * c * 4                // rec (packed u32)
                    + (size_t)NB * c * 4                // csr
                    + (size_t)NB * c                    // srec (u8)
                    + ((size_t)(2 * NB + 127) & ~63ull) * 4   // curD+curS (pad)
                    + (size_t)n * 4 * 4                 // deg, norm, row_start, row_cnt
                    + (size_t)ND * 2                    // yh
                    + (size_t)(128 + 3 * MAXOVF) * 4;   // counters + ovf + sovf
        if (need <= ws_size) { capb = c; break; }
    }

    if (NB <= NBMAX && capb > 0 && n < (1 << 24)) {
        unsigned int* rec  = (unsigned int*)d_ws;                    // NB*capb u32
        int*   csr         = (int*)(rec + (size_t)NB * capb);        // NB*capb
        unsigned char* srec = (unsigned char*)(csr + (size_t)NB * capb); // NB*capb u8
        int*   curD        = (int*)(srec + (((size_t)NB * capb + 3) & ~3ull)); // NB
        int*   curS        = curD + NB;                              // NB
        int*   deg         = curS + ((NB + 63) & ~63);               // n
        float* norm        = (float*)(deg + n);                      // n
        int*   row_start   = (int*)(norm + n);                       // n
        int*   row_cnt     = row_start + n;                          // n
        unsigned int* yh   = (unsigned int*)(row_cnt + n);           // ND/2 u32
        int*   ovf_cnt     = (int*)(yh + ND / 2);                    // [0]
        int*   sovf_cnt    = ovf_cnt + 64;                           // [0]
        int*   ovf         = sovf_cnt + 64;                          // 2*MAXOVF
        int*   sovf        = ovf + 2 * MAXOVF;                       // MAXOVF

        init_kernel<<<(NB + B - 1) / B, B, 0, stream>>>(curD, curS, ovf_cnt, sovf_cnt, NB, capb);
        partition_kernel<<<(E + EPB - 1) / EPB, B, 0, stream>>>(src, dst, curD, curS, rec, srec,
                                                                ovf_cnt, ovf, sovf_cnt, sovf,
                                                                E, NB, capb);
        combo_kernel<<<2 * NB, B, 0, stream>>>(rec, srec, curD, curS, csr, row_start,
                                               row_cnt, deg, n, NB, capb);
        spill_kernel<<<16, B, 0, stream>>>(sovf_cnt, sovf, deg);
        norm_y_kernel<<<(n * (D / 2) + B - 1) / B, B, 0, stream>>>((const float2*)x, deg,
                                                                   norm, yh, n);
        gather4_kernel<<<((n + 3) / 4 + 3) / 4, B, 0, stream>>>((const uint2*)yh,
                                                                (const float4*)x, csr,
                                                                row_start, row_cnt, norm,
                                                                (float4*)out, n);
        cleanup_kernel<<<64, B, 0, stream>>>(x, norm, ovf_cnt, ovf, out);
    } else {
        int*   deg  = (int*)d_ws;
        float* norm = (float*)d_ws + n;
        hipMemsetAsync(deg, 0, (size_t)n * sizeof(int), stream);
        fb_hist<<<(E + B - 1) / B, B, 0, stream>>>(src, deg, E);
        fb_norm<<<(n + B - 1) / B, B, 0, stream>>>(deg, norm, n);
        fb_init_out<<<(ND / 4 + B - 1) / B, B, 0, stream>>>((const float4*)x, (float4*)out, ND / 4);
        long long total = (long long)E * D;
        fb_scatter<<<(int)((total + B - 1) / B), B, 0, stream>>>(x, src, dst, norm, out, E);
    }
}

// Round 9
// 172.346 us; speedup vs baseline: 4.6165x; 1.0449x over previous
//
#include <hip/hip_runtime.h>

// GCN aggregation: out[t] = norm[t] * sum_{e:dst=t} norm[src]*x[src] + EPS*x[t]
// Round 9: (a) gather 8 nodes/wave (8 lanes x uint4 = 128B row -> 8 rows per vmem
// instruction); (b) combo's degcount blocks also compute norm + yh=bf16(norm*x)
// (bucket x-slice is contiguous -> coalesced) and absorb src-overflow entries,
// deleting the spill + norm_y launches and the deg array. 5 launches total.
constexpr int D        = 64;
constexpr float EPS    = 0.5f;
constexpr int BKT      = 128;
constexpr int CAPB_MAX = 2048;
constexpr int EPB      = 4096;   // edges per partition block
constexpr int NBMAX    = 1024;
constexpr int MAXOVF   = 65536;

__device__ __forceinline__ unsigned int f2bf(float f) {
    unsigned int u = __float_as_uint(f);
    return (u + 0x7FFFu + ((u >> 16) & 1u)) >> 16;   // RNE to bf16
}
__device__ __forceinline__ float bf2f_lo(unsigned int v) { return __uint_as_float(v << 16); }
__device__ __forceinline__ float bf2f_hi(unsigned int v) { return __uint_as_float(v & 0xFFFF0000u); }

// ---------------- main path ----------------

__global__ void init_kernel(int* __restrict__ curD, int* __restrict__ curS,
                            int* __restrict__ ovf_cnt, int* __restrict__ sovf_cnt,
                            int NB, int capb) {
    int i = blockIdx.x * blockDim.x + threadIdx.x;
    if (i < NB) { curD[i] = i * capb; curS[i] = i * capb; }
    if (i == 0) { *ovf_cnt = 0; *sovf_cnt = 0; }
}

__global__ __launch_bounds__(256)
void partition_kernel(const int* __restrict__ src, const int* __restrict__ dst,
                      int* __restrict__ curD, int* __restrict__ curS,
                      unsigned int* __restrict__ rec, unsigned char* __restrict__ srec,
                      int* __restrict__ ovf_cnt, int* __restrict__ ovf,
                      int* __restrict__ sovf_cnt, int* __restrict__ sovf,
                      int E, int NB, int capb) {
    __shared__ int histD[NBMAX];   // then reused as rankD
    __shared__ int histS[NBMAX];   // then reused as rankS
    __shared__ int startD[NBMAX];
    __shared__ int startS[NBMAX];
    const int base = blockIdx.x * EPB;
    const int tid  = threadIdx.x;
    for (int b = tid; b < NB; b += 256) { histD[b] = 0; histS[b] = 0; }
    __syncthreads();

    #pragma unroll
    for (int k = 0; k < EPB / 256; ++k) {
        int e = base + tid + k * 256;          // coalesced
        if (e < E) {
            atomicAdd(&histD[dst[e] >> 7], 1);
            atomicAdd(&histS[src[e] >> 7], 1);
        }
    }
    __syncthreads();
    for (int b = tid; b < NB; b += 256) {      // one global reserve atomic per (block,bucket)
        int c = histD[b];
        startD[b] = (c > 0) ? atomicAdd(&curD[b], c) : 0;
        histD[b] = 0;                          // reuse as rank
        int c2 = histS[b];
        startS[b] = (c2 > 0) ? atomicAdd(&curS[b], c2) : 0;
        histS[b] = 0;
    }
    __syncthreads();
    #pragma unroll
    for (int k = 0; k < EPB / 256; ++k) {
        int e = base + tid + k * 256;
        if (e < E) {
            int s = src[e], t = dst[e];
            int bD = t >> 7;
            int r  = atomicAdd(&histD[bD], 1);
            int pD = startD[bD] + r;
            if (pD < (bD + 1) * capb) {
                rec[pD] = ((unsigned int)s << 7) | (unsigned int)(t & (BKT - 1));
            } else {
                int i = atomicAdd(ovf_cnt, 1);
                if (i < MAXOVF) { ovf[2 * i] = s; ovf[2 * i + 1] = t; }
            }
            int bS = s >> 7;
            int r2 = atomicAdd(&histS[bS], 1);
            int pS = startS[bS] + r2;
            if (pS < (bS + 1) * capb) {
                srec[pS] = (unsigned char)(s & (BKT - 1));
            } else {
                int i = atomicAdd(sovf_cnt, 1);
                if (i < MAXOVF) sovf[i] = s;
            }
        }
    }
}

// grid = 2*NB. Blocks [0,NB): LDS counting sort of dst-regions -> per-node CSR.
// Blocks [NB,2NB): out-degree count from src-regions (+ rare sovf entries) ->
// norm + yh = bf16(norm*x) for the bucket's contiguous node range.
__global__ __launch_bounds__(256)
void combo_kernel(const unsigned int* __restrict__ rec, const unsigned char* __restrict__ srec,
                  const int* __restrict__ curD, const int* __restrict__ curS,
                  int* __restrict__ csr, int* __restrict__ row_start,
                  int* __restrict__ row_cnt, const float2* __restrict__ x2,
                  float* __restrict__ norm, unsigned int* __restrict__ yh,
                  const int* __restrict__ sovf_cnt, const int* __restrict__ sovf,
                  int n, int NB, int capb) {
    __shared__ unsigned int recs[CAPB_MAX];   // 8 KB
    __shared__ int srcs[CAPB_MAX];            // 8 KB
    __shared__ int hist[BKT];
    __shared__ int scanv[BKT];
    __shared__ int rankb[BKT];
    __shared__ float nrm[BKT];
    const int tid = threadIdx.x;

    if (blockIdx.x >= NB) {
        // ---- degcount + norm + yh path ----
        int b = blockIdx.x - NB;
        int cnt = curS[b] - b * capb;
        if (cnt > capb) cnt = capb;
        if (tid < BKT) hist[tid] = 0;
        __syncthreads();
        for (int i = tid; i < cnt; i += 256)
            atomicAdd(&hist[srec[(size_t)b * capb + i]], 1);
        __syncthreads();
        int oc = *sovf_cnt;                    // expected 0
        if (oc > 0) {
            if (oc > MAXOVF) oc = MAXOVF;
            for (int i = tid; i < oc; i += 256) {
                int s = sovf[i];
                if ((s >> 7) == b) atomicAdd(&hist[s & (BKT - 1)], 1);
            }
            __syncthreads();
        }
        if (tid < BKT) {
            int node = b * BKT + tid;
            float nm = rsqrtf(fmaxf((float)hist[tid], 1.0f));
            nrm[tid] = nm;
            if (node < n) norm[node] = nm;
        }
        __syncthreads();
        int nodes = n - b * BKT;
        if (nodes > BKT) nodes = BKT;
        if (nodes < 0) nodes = 0;
        int total = nodes * (D / 2);           // float2 elements in this bucket
        size_t gbase = (size_t)b * BKT * (D / 2);
        for (int i = tid; i < total; i += 256) {   // contiguous -> coalesced
            float2 v = x2[gbase + i];
            float nm = nrm[i >> 5];
            yh[gbase + i] = f2bf(v.x * nm) | (f2bf(v.y * nm) << 16);
        }
        return;
    }

    // ---- sort path ----
    const int b = blockIdx.x;
    int cnt = curD[b] - b * capb;
    if (cnt > capb) cnt = capb;
    for (int i = tid; i < cnt; i += 256) recs[i] = rec[(size_t)b * capb + i];
    if (tid < BKT) hist[tid] = 0;
    __syncthreads();
    for (int i = tid; i < cnt; i += 256) atomicAdd(&hist[recs[i] & (BKT - 1)], 1);
    __syncthreads();
    if (tid < BKT) scanv[tid] = hist[tid];
    __syncthreads();
    #pragma unroll
    for (int off = 1; off < BKT; off <<= 1) {          // Hillis-Steele inclusive scan
        int t = 0;
        if (tid < BKT && tid >= off) t = scanv[tid - off];
        __syncthreads();
        if (tid < BKT) scanv[tid] += t;
        __syncthreads();
    }
    if (tid < BKT) {
        int excl = scanv[tid] - hist[tid];
        rankb[tid] = excl;
        int node = b * BKT + tid;
        if (node < n) {
            row_start[node] = b * capb + excl;
            row_cnt[node]   = hist[tid];
        }
    }
    __syncthreads();
    for (int i = tid; i < cnt; i += 256) {
        unsigned int v = recs[i];
        int pos = atomicAdd(&rankb[v & (BKT - 1)], 1);
        srcs[pos] = (int)(v >> 7);
    }
    __syncthreads();
    for (int i = tid; i < cnt; i += 256) csr[(size_t)b * capb + i] = srcs[i];
}

// 8 nodes per wave: oct (8 lanes) x uint4 = one 128B yh row -> 8 rows per vmem inst.
// Uniform loop count = wave-max(cnt); out-of-range iterations masked to zero.
__global__ __launch_bounds__(256)
void gather8_kernel(const uint4* __restrict__ yr4, const float4* __restrict__ x4,
                    const int* __restrict__ csr, const int* __restrict__ row_start,
                    const int* __restrict__ row_cnt, const float* __restrict__ norm,
                    float4* __restrict__ out4, int n) {
    int wid  = (blockIdx.x * blockDim.x + threadIdx.x) >> 6;
    int lane = threadIdx.x & 63;
    int fl   = lane & 7;               // uint4 index within row (8 x 16B = 128B)
    int node = wid * 8 + (lane >> 3);  // oct -> node
    bool valid = node < n;
    int rs  = valid ? row_start[node] : 0;
    int cnt = valid ? row_cnt[node] : 0;
    int m = cnt;
    m = max(m, __shfl_xor(m, 8));
    m = max(m, __shfl_xor(m, 16));
    m = max(m, __shfl_xor(m, 32));
    float a0 = 0.f, a1 = 0.f, a2 = 0.f, a3 = 0.f, a4 = 0.f, a5 = 0.f, a6 = 0.f, a7 = 0.f;
    for (int k = 0; k < m; k += 4) {
        #pragma unroll
        for (int j = 0; j < 4; ++j) {
            int kj = k + j;
            bool take = kj < cnt;
            int s = csr[rs + (take ? kj : 0)];
            s = take ? s : 0;
            uint4 v = yr4[(size_t)s * 8 + fl];
            if (!take) { v.x = 0u; v.y = 0u; v.z = 0u; v.w = 0u; }
            a0 += bf2f_lo(v.x); a1 += bf2f_hi(v.x);
            a2 += bf2f_lo(v.y); a3 += bf2f_hi(v.y);
            a4 += bf2f_lo(v.z); a5 += bf2f_hi(v.z);
            a6 += bf2f_lo(v.w); a7 += bf2f_hi(v.w);
        }
    }
    if (valid) {
        float nt = norm[node];
        size_t base = (size_t)node * 16 + fl * 2;
        float4 xv0 = x4[base], xv1 = x4[base + 1];
        float4 r0, r1;
        r0.x = a0 * nt + EPS * xv0.x;  r0.y = a1 * nt + EPS * xv0.y;
        r0.z = a2 * nt + EPS * xv0.z;  r0.w = a3 * nt + EPS * xv0.w;
        r1.x = a4 * nt + EPS * xv1.x;  r1.y = a5 * nt + EPS * xv1.y;
        r1.z = a6 * nt + EPS * xv1.z;  r1.w = a7 * nt + EPS * xv1.w;
        out4[base] = r0;               // coalesced: 32B/lane, contiguous per wave
        out4[base + 1] = r1;
    }
}

// rare: dst-bucket overflow edges (expected 0)
__global__ void cleanup_kernel(const float* __restrict__ x, const float* __restrict__ norm,
                               const int* __restrict__ ovf_cnt, const int* __restrict__ ovf,
                               float* __restrict__ out) {
    int cnt = *ovf_cnt;
    if (cnt > MAXOVF) cnt = MAXOVF;
    long long total = (long long)cnt * D;
    long long stride = (long long)gridDim.x * blockDim.x;
    for (long long i = blockIdx.x * (long long)blockDim.x + threadIdx.x; i < total; i += stride) {
        int e = (int)(i >> 6), d = (int)(i & 63);
        int s = ovf[2 * e], t = ovf[2 * e + 1];
        atomicAdd(&out[(size_t)t * D + d], norm[s] * norm[t] * x[(size_t)s * D + d]);
    }
}

// ---------------- tiny-ws / big-n fallback (round-1 proven) ----------------

__global__ void fb_hist(const int* __restrict__ src, int* __restrict__ deg, int E) {
    int e = blockIdx.x * blockDim.x + threadIdx.x;
    if (e < E) atomicAdd(&deg[src[e]], 1);
}
__global__ void fb_norm(const int* __restrict__ deg, float* __restrict__ norm, int n) {
    int i = blockIdx.x * blockDim.x + threadIdx.x;
    if (i < n) norm[i] = rsqrtf(fmaxf((float)deg[i], 1.0f));
}
__global__ void fb_init_out(const float4* __restrict__ x, float4* __restrict__ out, int n4) {
    int i = blockIdx.x * blockDim.x + threadIdx.x;
    if (i < n4) {
        float4 v = x[i];
        out[i] = make_float4(v.x * EPS, v.y * EPS, v.z * EPS, v.w * EPS);
    }
}
__global__ void fb_scatter(const float* __restrict__ x, const int* __restrict__ src,
                           const int* __restrict__ dst, const float* __restrict__ norm,
                           float* __restrict__ out, int E) {
    long long tid = (long long)blockIdx.x * blockDim.x + threadIdx.x;
    int e = (int)(tid >> 6), d = (int)(tid & 63);
    if (e < E) {
        int s = src[e], t = dst[e];
        atomicAdd(&out[(size_t)t * D + d], norm[s] * norm[t] * x[(size_t)s * D + d]);
    }
}

// ---------------- launcher ----------------

extern "C" void kernel_launch(void* const* d_in, const int* in_sizes, int n_in,
                              void* d_out, int out_size, void* d_ws, size_t ws_size,
                              hipStream_t stream) {
    const float* x   = (const float*)d_in[0];
    const int*   src = (const int*)d_in[1];
    const int*   dst = (const int*)d_in[2];
    float* out = (float*)d_out;

    const int ND = in_sizes[0];
    const int E  = in_sizes[1];
    const int n  = ND / D;
    const int NB = (n + BKT - 1) / BKT;
    constexpr int B = 256;

    int capb = 0;
    for (int c : {2048, 1792}) {
        size_t need = (size_t)NB * c * 4                // rec (packed u32)
                    + (size_t)NB * c * 4                // csr
                    + (size_t)NB * c                    // srec (u8)
                    + ((size_t)(2 * NB + 127) & ~63ull) * 4
                    + (size_t)n * 4 * 3                 // norm, row_start, row_cnt
                    + (size_t)ND * 2                    // yh
                    + (size_t)(128 + 3 * MAXOVF) * 4;
        if (need <= ws_size) { capb = c; break; }
    }

    if (NB <= NBMAX && capb > 0 && n < (1 << 24)) {
        unsigned int* rec   = (unsigned int*)d_ws;                       // NB*capb u32
        int*   csr          = (int*)(rec + (size_t)NB * capb);           // NB*capb
        unsigned char* srec = (unsigned char*)(csr + (size_t)NB * capb); // NB*capb u8
        int*   curD         = (int*)(srec + (((size_t)NB * capb + 3) & ~3ull)); // NB
        int*   curS         = curD + NB;                                 // NB
        float* norm         = (float*)(curS + ((NB + 63) & ~63));        // n
        int*   row_start    = (int*)(norm + n);                          // n
        int*   row_cnt      = row_start + n;                             // n
        unsigned int* yh    = (unsigned int*)(row_cnt + n);              // ND/2 u32
        int*   ovf_cnt      = (int*)(yh + ND / 2);                       // [0]
        int*   sovf_cnt     = ovf_cnt + 64;                              // [0]
        int*   ovf          = sovf_cnt + 64;                             // 2*MAXOVF
        int*   sovf         = ovf + 2 * MAXOVF;                          // MAXOVF

        init_kernel<<<(NB + B - 1) / B, B, 0, stream>>>(curD, curS, ovf_cnt, sovf_cnt, NB, capb);
        partition_kernel<<<(E + EPB - 1) / EPB, B, 0, stream>>>(src, dst, curD, curS, rec, srec,
                                                                ovf_cnt, ovf, sovf_cnt, sovf,
                                                                E, NB, capb);
        combo_kernel<<<2 * NB, B, 0, stream>>>(rec, srec, curD, curS, csr, row_start, row_cnt,
                                               (const float2*)x, norm, yh, sovf_cnt, sovf,
                                               n, NB, capb);
        // 8 nodes/wave -> 32 nodes/block
        gather8_kernel<<<(n + 31) / 32, B, 0, stream>>>((const uint4*)yh, (const float4*)x,
                                                        csr, row_start, row_cnt, norm,
                                                        (float4*)out, n);
        cleanup_kernel<<<64, B, 0, stream>>>(x, norm, ovf_cnt, ovf, out);
    } else {
        int*   deg  = (int*)d_ws;
        float* norm = (float*)d_ws + n;
        hipMemsetAsync(deg, 0, (size_t)n * sizeof(int), stream);
        fb_hist<<<(E + B - 1) / B, B, 0, stream>>>(src, deg, E);
        fb_norm<<<(n + B - 1) / B, B, 0, stream>>>(deg, norm, n);
        fb_init_out<<<(ND / 4 + B - 1) / B, B, 0, stream>>>((const float4*)x, (float4*)out, ND / 4);
        long long total = (long long)E * D;
        fb_scatter<<<(int)((total + B - 1) / B), B, 0, stream>>>(x, src, dst, norm, out, E);
    }
}